// Round 7
// baseline (2629.792 us; speedup 1.0000x reference)
//
#include <hip/hip_runtime.h>

#define T_TOK 8192
#define DIN   4096
#define DOUTF 4096
#define RANK  16

#define BM 256
#define BN 256
#define BK 32
#define NT (DIN / BK)  // 128 K-tiles

typedef __attribute__((ext_vector_type(4))) float f32x4;
typedef __attribute__((ext_vector_type(8))) short bf16x8;
typedef __attribute__((ext_vector_type(8))) unsigned short u16x8;

#define GLB_PTR(p) ((const __attribute__((address_space(1))) void*)(p))
#define LDS_PTR(p) ((__attribute__((address_space(3))) void*)(p))

__device__ __forceinline__ unsigned short f2bf(float f) {
  unsigned u = __float_as_uint(f);
  u = (u + 0x7fffu + ((u >> 16) & 1u)) >> 16;  // RNE
  return (unsigned short)u;
}

// ---------------------------------------------------------------- fp32 -> bf16
__global__ __launch_bounds__(256) void cvt_f32_bf16(const float* __restrict__ in,
                                                    unsigned short* __restrict__ out,
                                                    int n8) {
  const int stride = gridDim.x * blockDim.x;
  for (int i = blockIdx.x * blockDim.x + threadIdx.x; i < n8; i += stride) {
    const float4* p = (const float4*)(in + (size_t)i * 8);
    float4 a = p[0], b = p[1];
    u16x8 r;
    r[0] = f2bf(a.x); r[1] = f2bf(a.y); r[2] = f2bf(a.z); r[3] = f2bf(a.w);
    r[4] = f2bf(b.x); r[5] = f2bf(b.y); r[6] = f2bf(b.z); r[7] = f2bf(b.w);
    *(u16x8*)(out + (size_t)i * 8) = r;
  }
}

// ----------------- h'[t,r] = scaling * x @ wa[id_t]; emits x bf16 + h' bf16 ---
__global__ __launch_bounds__(256) void lora_h(const float* __restrict__ x,
                                              const float* __restrict__ wa,
                                              const float* __restrict__ scaling,
                                              const int* __restrict__ segment,
                                              const int* __restrict__ lora_ids,
                                              float* __restrict__ hbuf,
                                              unsigned short* __restrict__ hb16,
                                              int* __restrict__ tokid,
                                              unsigned short* __restrict__ xb) {
  const int lane = threadIdx.x & 63;
  const int wave = threadIdx.x >> 6;
  const int t0 = blockIdx.x * 16 + wave * 4;

  int ids[4]; float sc[4];
#pragma unroll
  for (int q = 0; q < 4; ++q) {
    int t = t0 + q;
    int s = 0;
#pragma unroll
    for (int i = 1; i < 8; ++i)
      if (t >= segment[i]) s = i;
    int id = lora_ids[s];
    ids[q] = id;
    sc[q] = scaling[id];
  }

  float acc[4][16];
#pragma unroll
  for (int q = 0; q < 4; ++q)
#pragma unroll
    for (int r = 0; r < 16; ++r) acc[q][r] = 0.f;

  const bool same = (ids[0] == ids[1]) && (ids[1] == ids[2]) && (ids[2] == ids[3]);
  const int dbase = lane * 4;

  if (same) {
    const float* wrow = wa + (size_t)ids[0] * DIN * RANK;
#pragma unroll 2
    for (int it = 0; it < 16; ++it) {
      const int d = it * 256 + dbase;
      f32x4 xv[4];
#pragma unroll
      for (int q = 0; q < 4; ++q) {
        xv[q] = *(const f32x4*)(x + (size_t)(t0 + q) * DIN + d);
        ushort4 s4 = {f2bf(xv[q][0]), f2bf(xv[q][1]), f2bf(xv[q][2]), f2bf(xv[q][3])};
        *(ushort4*)(xb + (size_t)(t0 + q) * DIN + d) = s4;
      }
#pragma unroll
      for (int dd = 0; dd < 4; ++dd) {
        const f32x4* wp = (const f32x4*)(wrow + (size_t)(d + dd) * RANK);
        f32x4 w0 = wp[0], w1 = wp[1], w2 = wp[2], w3 = wp[3];
#pragma unroll
        for (int q = 0; q < 4; ++q) {
          const float xs = xv[q][dd];
#pragma unroll
          for (int r = 0; r < 4; ++r) {
            acc[q][r]      += xs * w0[r];
            acc[q][r + 4]  += xs * w1[r];
            acc[q][r + 8]  += xs * w2[r];
            acc[q][r + 12] += xs * w3[r];
          }
        }
      }
    }
  } else {
#pragma unroll
    for (int q = 0; q < 4; ++q) {
      const float* wrow = wa + (size_t)ids[q] * DIN * RANK;
      for (int it = 0; it < 16; ++it) {
        const int d = it * 256 + dbase;
        f32x4 xv = *(const f32x4*)(x + (size_t)(t0 + q) * DIN + d);
        ushort4 s4 = {f2bf(xv[0]), f2bf(xv[1]), f2bf(xv[2]), f2bf(xv[3])};
        *(ushort4*)(xb + (size_t)(t0 + q) * DIN + d) = s4;
#pragma unroll
        for (int dd = 0; dd < 4; ++dd) {
          const f32x4* wp = (const f32x4*)(wrow + (size_t)(d + dd) * RANK);
          f32x4 w0 = wp[0], w1 = wp[1], w2 = wp[2], w3 = wp[3];
          const float xs = xv[dd];
#pragma unroll
          for (int r = 0; r < 4; ++r) {
            acc[q][r]      += xs * w0[r];
            acc[q][r + 4]  += xs * w1[r];
            acc[q][r + 8]  += xs * w2[r];
            acc[q][r + 12] += xs * w3[r];
          }
        }
      }
    }
  }

#pragma unroll
  for (int q = 0; q < 4; ++q) {
#pragma unroll
    for (int r = 0; r < 16; ++r) {
      float v = acc[q][r];
      v += __shfl_xor(v, 1);
      v += __shfl_xor(v, 2);
      v += __shfl_xor(v, 4);
      v += __shfl_xor(v, 8);
      v += __shfl_xor(v, 16);
      v += __shfl_xor(v, 32);
      acc[q][r] = v;
    }
    if (lane == 0) {
      int t = t0 + q;
      tokid[t] = ids[q];
#pragma unroll
      for (int r = 0; r < 16; ++r) {
        float v = sc[q] * acc[q][r];
        hbuf[t * RANK + r] = v;
        hb16[t * RANK + r] = f2bf(v);
      }
    }
  }
}

// ------------------------------------------------------------- main fused GEMM
// 256x256 tile, BK=32, 8 waves (2M x 4N), per-wave output 128x64.
// PIVOT (r7): TLP over choreography. 2-deep double buffer = 64 KB LDS ->
// 2 blocks/CU (16 waves/CU); when one block sits at its barrier the other
// block's MFMA cluster fills the SIMD (m114/m103 mechanism). Counted waits
// preserved with 2-deep by placing the stage AFTER the reads' barrier:
//   reads(buf p) -> 2x setprio MFMA x16 -> barrier1 (reads of p drained)
//   -> STAGE(p, t+2) -> vmcnt(4) (tile t+1 landed; t+2 in flight, never 0)
//   -> barrier2 -> next tile reads buf p^1.
// XOR swizzle (64B rows): phys 16B-chunk = logical ^ ((row>>1)&3) on BOTH the
// staging source and the ds_read (rule #21; rounds 4-6 proven 0 conflicts).
__global__ __launch_bounds__(512, 4) void gemm_fused(const unsigned short* __restrict__ A_,
                                                     const unsigned short* __restrict__ B_,
                                                     const float* __restrict__ bias,
                                                     const float* __restrict__ hbuf,
                                                     const unsigned short* __restrict__ hb16,
                                                     const int* __restrict__ tokid,
                                                     const float* __restrict__ wbt,
                                                     float* __restrict__ out) {
  __shared__ __align__(16) unsigned short As[2][BM * BK];  // 2 x 16 KB
  __shared__ __align__(16) unsigned short Bs[2][BN * BK];  // 2 x 16 KB
  __shared__ int s_nb;

  const int tid = threadIdx.x;
  const int lane = tid & 63;
  const int wave = tid >> 6;   // 0..7
  const int wr = wave >> 2;    // 0..1  M half
  const int wn = wave & 3;     // 0..3  N quarter

  // XCD-aware bijective swizzle: 512 blocks, 64-block chunk per XCD
  const int bsw = (blockIdx.x & 7) * 64 + (blockIdx.x >> 3);
  const int brow = (bsw >> 4) * BM;   // 32 M-blocks
  const int bcol = (bsw & 15) * BN;   // 16 N-blocks

  f32x4 acc[8][4] = {};

  const int g = lane >> 4;              // k-group 0..3 (8 k each)
  const int rsel = lane & 15;           // fragment row select
  const int rphase = (rsel >> 1) & 3;   // swizzle phase for read rows
  const int phys = (g ^ rphase) * 8;

#define STAGE(p, kt)                                                                   \
  {                                                                                    \
    _Pragma("unroll")                                                                  \
    for (int i = 0; i < 2; ++i) {                                                      \
      const int lin = i * 512 + tid;           /* 0..1023 */                           \
      const int r = lin >> 2;                  /* row 0..255 */                        \
      const int klog = ((lin & 3) ^ ((r >> 1) & 3)) * 8;                               \
      const unsigned short* gA = A_ + (size_t)(brow + r) * DIN + (kt) + klog;          \
      const unsigned short* gB = B_ + (size_t)(bcol + r) * DIN + (kt) + klog;          \
      __builtin_amdgcn_global_load_lds(GLB_PTR(gA), LDS_PTR(&As[p][lin * 8]), 16, 0, 0); \
      __builtin_amdgcn_global_load_lds(GLB_PTR(gB), LDS_PTR(&Bs[p][lin * 8]), 16, 0, 0); \
    }                                                                                  \
  }

  STAGE(0, 0);
  STAGE(1, BK);
  asm volatile("s_waitcnt vmcnt(4)" ::: "memory");  // tile 0 landed; tile 1 in flight
  __builtin_amdgcn_s_barrier();
  asm volatile("" ::: "memory");

  for (int t = 0; t < NT; ++t) {
    const int p = t & 1;
    const unsigned short* Asp = As[p];
    const unsigned short* Bsp = Bs[p];

    // all 12 ds_reads issued upfront; compiler's counted lgkmcnt lets the
    // first MFMA cluster start while later reads are still in flight
    bf16x8 bfr[4];
#pragma unroll
    for (int n = 0; n < 4; ++n)
      bfr[n] = *(const bf16x8*)(Bsp + (wn * 64 + n * 16 + rsel) * BK + phys);
    bf16x8 afr0[4], afr1[4];
#pragma unroll
    for (int mi = 0; mi < 4; ++mi)
      afr0[mi] = *(const bf16x8*)(Asp + (wr * 128 + mi * 16 + rsel) * BK + phys);
#pragma unroll
    for (int mi = 0; mi < 4; ++mi)
      afr1[mi] = *(const bf16x8*)(Asp + (wr * 128 + (4 + mi) * 16 + rsel) * BK + phys);

    __builtin_amdgcn_s_setprio(1);
#pragma unroll
    for (int mi = 0; mi < 4; ++mi)
#pragma unroll
      for (int n = 0; n < 4; ++n)
        acc[mi][n] = __builtin_amdgcn_mfma_f32_16x16x32_bf16(afr0[mi], bfr[n], acc[mi][n], 0, 0, 0);
    __builtin_amdgcn_s_setprio(0);

    __builtin_amdgcn_s_setprio(1);
#pragma unroll
    for (int mi = 0; mi < 4; ++mi)
#pragma unroll
      for (int n = 0; n < 4; ++n)
        acc[4 + mi][n] = __builtin_amdgcn_mfma_f32_16x16x32_bf16(afr1[mi], bfr[n], acc[4 + mi][n], 0, 0, 0);
    __builtin_amdgcn_s_setprio(0);

    // barrier1: every wave's reads of buf p are complete (consumed by MFMAs)
    asm volatile("" ::: "memory");
    __builtin_amdgcn_s_barrier();
    asm volatile("" ::: "memory");

    // refill the buffer just read; then counted wait: tile t+1 landed,
    // tile t+2's 4 loads in flight (never drains to 0 in the main loop)
    if (t + 2 < NT) {
      STAGE(p, (t + 2) * BK);
      asm volatile("s_waitcnt vmcnt(4)" ::: "memory");
    } else if (t + 1 < NT) {
      asm volatile("s_waitcnt vmcnt(0)" ::: "memory");
    }
    __builtin_amdgcn_s_barrier();
    asm volatile("" ::: "memory");
  }

  // ---- epilogue -------------------------------------------------------------
  const int rb = brow + wr * 128;
  const int cb = bcol + wn * 64;
  const int crow = g * 4;          // C/D row = (lane>>4)*4 + j
  const int ccol = rsel;

  // count adapter transitions in this block's 256 rows
  if (tid == 0) s_nb = 0;
  __syncthreads();
  if (tid >= 1 && tid < BM) {
    if (tokid[brow + tid] != tokid[brow + tid - 1]) atomicAdd(&s_nb, 1);
  }
  __syncthreads();
  const int nb = s_nb;
  const int idLo = tokid[brow];
  const int idHi = tokid[brow + BM - 1];

  float biasn[4];
#pragma unroll
  for (int n = 0; n < 4; ++n) biasn[n] = bias[cb + n * 16 + ccol];

  if (nb <= 1) {
    // ---- MFMA K=32 extension: k<16 -> adapter idLo, k>=16 -> adapter idHi
    const int myId = (g < 2) ? idLo : idHi;
    const int maskId = (g < 2) ? idLo : ((nb == 0) ? 0x80000000 : idHi);
    const float* wbase = wbt + (size_t)myId * RANK * DOUTF + (size_t)((g & 1) * 8) * DOUTF;
    bf16x8 bext[4];
#pragma unroll
    for (int n = 0; n < 4; ++n) {
      const int col = cb + n * 16 + ccol;
#pragma unroll
      for (int j = 0; j < 8; ++j)
        bext[n][j] = (short)f2bf(wbase[(size_t)j * DOUTF + col]);
    }
#pragma unroll
    for (int m = 0; m < 8; ++m) {
      const int row = rb + m * 16 + rsel;
      const int rid = tokid[row];
      bf16x8 av = {};
      if (rid == maskId)
        av = *(const bf16x8*)(hb16 + (size_t)row * RANK + (g & 1) * 8);
#pragma unroll
      for (int n = 0; n < 4; ++n)
        acc[m][n] = __builtin_amdgcn_mfma_f32_16x16x32_bf16(av, bext[n], acc[m][n], 0, 0, 0);
    }
#pragma unroll
    for (int m = 0; m < 8; ++m) {
#pragma unroll
      for (int j = 0; j < 4; ++j) {
        const int row = rb + m * 16 + crow + j;
        float* orow = out + (size_t)row * DOUTF;
#pragma unroll
        for (int n = 0; n < 4; ++n)
          orow[cb + n * 16 + ccol] = acc[m][n][j] + biasn[n];
      }
    }
  } else {
    // ---- rare fallback: per-row scalar LoRA
#pragma unroll
    for (int m = 0; m < 8; ++m) {
#pragma unroll
      for (int j = 0; j < 4; ++j) {
        const int row = rb + m * 16 + crow + j;
        const float4* hp = (const float4*)(hbuf + (size_t)row * RANK);
        float4 h0 = hp[0], h1 = hp[1], h2 = hp[2], h3 = hp[3];
        float hv[16] = {h0.x, h0.y, h0.z, h0.w, h1.x, h1.y, h1.z, h1.w,
                        h2.x, h2.y, h2.z, h2.w, h3.x, h3.y, h3.z, h3.w};
        const float* wrow = wbt + (size_t)tokid[row] * RANK * DOUTF;
        float* orow = out + (size_t)row * DOUTF;
#pragma unroll
        for (int n = 0; n < 4; ++n) {
          const int col = cb + n * 16 + ccol;
          float v = acc[m][n][j] + biasn[n];
#pragma unroll
          for (int r = 0; r < 16; ++r) v += hv[r] * wrow[(size_t)r * DOUTF + col];
          orow[col] = v;
        }
      }
    }
  }
#undef STAGE
}

// ---------------------------------------------------------------------- launch
extern "C" void kernel_launch(void* const* d_in, const int* in_sizes, int n_in,
                              void* d_out, int out_size, void* d_ws, size_t ws_size,
                              hipStream_t stream) {
  const float* x       = (const float*)d_in[0];
  const float* base_w  = (const float*)d_in[1];
  const float* base_b  = (const float*)d_in[2];
  const float* wa      = (const float*)d_in[3];
  const float* wb      = (const float*)d_in[4];
  const float* scaling = (const float*)d_in[5];
  const int*   segment = (const int*)d_in[6];
  const int*   lora_id = (const int*)d_in[7];
  float* out = (float*)d_out;

  char* ws = (char*)d_ws;
  unsigned short* xb   = (unsigned short*)ws;                                  // 64 MB
  unsigned short* wbf  = (unsigned short*)(ws + (size_t)T_TOK * DIN * 2);      // 32 MB
  float* hbuf          = (float*)(ws + (size_t)T_TOK * DIN * 2 + (size_t)DOUTF * DIN * 2);
  int* tokid           = (int*)((char*)hbuf + (size_t)T_TOK * RANK * 4);
  unsigned short* hb16 = (unsigned short*)((char*)tokid + (size_t)T_TOK * 4);

  cvt_f32_bf16<<<2048, 256, 0, stream>>>(base_w, wbf, (DOUTF * DIN) / 8);
  lora_h<<<T_TOK / 16, 256, 0, stream>>>(x, wa, scaling, segment, lora_id, hbuf, hb16,
                                         tokid, xb);
  gemm_fused<<<(T_TOK / BM) * (DOUTF / BN), 512, 0, stream>>>(xb, wbf, base_b, hbuf,
                                                              hb16, tokid, wb, out);
}

// Round 8
// 418.451 us; speedup vs baseline: 6.2846x; 6.2846x over previous
//
#include <hip/hip_runtime.h>

#define T_TOK 8192
#define DIN   4096
#define DOUTF 4096
#define RANK  16

#define BM 256
#define BN 256
#define BK 64
#define NT (DIN / BK)   // 64 K-tiles
#define NPAIR (NT / 2)  // 32 iterations, 2 K-tiles each

typedef __attribute__((ext_vector_type(4))) float f32x4;
typedef __attribute__((ext_vector_type(8))) short bf16x8;
typedef __attribute__((ext_vector_type(8))) unsigned short u16x8;

#define GLB_PTR(p) ((const __attribute__((address_space(1))) void*)(p))
#define LDS_PTR(p) ((__attribute__((address_space(3))) void*)(p))

__device__ __forceinline__ unsigned short f2bf(float f) {
  unsigned u = __float_as_uint(f);
  u = (u + 0x7fffu + ((u >> 16) & 1u)) >> 16;  // RNE
  return (unsigned short)u;
}

// ---------------------------------------------------------------- fp32 -> bf16
__global__ __launch_bounds__(256) void cvt_f32_bf16(const float* __restrict__ in,
                                                    unsigned short* __restrict__ out,
                                                    int n8) {
  const int stride = gridDim.x * blockDim.x;
  for (int i = blockIdx.x * blockDim.x + threadIdx.x; i < n8; i += stride) {
    const float4* p = (const float4*)(in + (size_t)i * 8);
    float4 a = p[0], b = p[1];
    u16x8 r;
    r[0] = f2bf(a.x); r[1] = f2bf(a.y); r[2] = f2bf(a.z); r[3] = f2bf(a.w);
    r[4] = f2bf(b.x); r[5] = f2bf(b.y); r[6] = f2bf(b.z); r[7] = f2bf(b.w);
    *(u16x8*)(out + (size_t)i * 8) = r;
  }
}

// ----------------- h'[t,r] = scaling * x @ wa[id_t]; emits x bf16 + h' bf16 ---
__global__ __launch_bounds__(256) void lora_h(const float* __restrict__ x,
                                              const float* __restrict__ wa,
                                              const float* __restrict__ scaling,
                                              const int* __restrict__ segment,
                                              const int* __restrict__ lora_ids,
                                              float* __restrict__ hbuf,
                                              unsigned short* __restrict__ hb16,
                                              int* __restrict__ tokid,
                                              unsigned short* __restrict__ xb) {
  const int lane = threadIdx.x & 63;
  const int wave = threadIdx.x >> 6;
  const int t0 = blockIdx.x * 16 + wave * 4;

  int ids[4]; float sc[4];
#pragma unroll
  for (int q = 0; q < 4; ++q) {
    int t = t0 + q;
    int s = 0;
#pragma unroll
    for (int i = 1; i < 8; ++i)
      if (t >= segment[i]) s = i;
    int id = lora_ids[s];
    ids[q] = id;
    sc[q] = scaling[id];
  }

  float acc[4][16];
#pragma unroll
  for (int q = 0; q < 4; ++q)
#pragma unroll
    for (int r = 0; r < 16; ++r) acc[q][r] = 0.f;

  const bool same = (ids[0] == ids[1]) && (ids[1] == ids[2]) && (ids[2] == ids[3]);
  const int dbase = lane * 4;

  if (same) {
    const float* wrow = wa + (size_t)ids[0] * DIN * RANK;
#pragma unroll 2
    for (int it = 0; it < 16; ++it) {
      const int d = it * 256 + dbase;
      f32x4 xv[4];
#pragma unroll
      for (int q = 0; q < 4; ++q) {
        xv[q] = *(const f32x4*)(x + (size_t)(t0 + q) * DIN + d);
        ushort4 s4 = {f2bf(xv[q][0]), f2bf(xv[q][1]), f2bf(xv[q][2]), f2bf(xv[q][3])};
        *(ushort4*)(xb + (size_t)(t0 + q) * DIN + d) = s4;
      }
#pragma unroll
      for (int dd = 0; dd < 4; ++dd) {
        const f32x4* wp = (const f32x4*)(wrow + (size_t)(d + dd) * RANK);
        f32x4 w0 = wp[0], w1 = wp[1], w2 = wp[2], w3 = wp[3];
#pragma unroll
        for (int q = 0; q < 4; ++q) {
          const float xs = xv[q][dd];
#pragma unroll
          for (int r = 0; r < 4; ++r) {
            acc[q][r]      += xs * w0[r];
            acc[q][r + 4]  += xs * w1[r];
            acc[q][r + 8]  += xs * w2[r];
            acc[q][r + 12] += xs * w3[r];
          }
        }
      }
    }
  } else {
#pragma unroll
    for (int q = 0; q < 4; ++q) {
      const float* wrow = wa + (size_t)ids[q] * DIN * RANK;
      for (int it = 0; it < 16; ++it) {
        const int d = it * 256 + dbase;
        f32x4 xv = *(const f32x4*)(x + (size_t)(t0 + q) * DIN + d);
        ushort4 s4 = {f2bf(xv[0]), f2bf(xv[1]), f2bf(xv[2]), f2bf(xv[3])};
        *(ushort4*)(xb + (size_t)(t0 + q) * DIN + d) = s4;
#pragma unroll
        for (int dd = 0; dd < 4; ++dd) {
          const f32x4* wp = (const f32x4*)(wrow + (size_t)(d + dd) * RANK);
          f32x4 w0 = wp[0], w1 = wp[1], w2 = wp[2], w3 = wp[3];
          const float xs = xv[dd];
#pragma unroll
          for (int r = 0; r < 4; ++r) {
            acc[q][r]      += xs * w0[r];
            acc[q][r + 4]  += xs * w1[r];
            acc[q][r + 8]  += xs * w2[r];
            acc[q][r + 12] += xs * w3[r];
          }
        }
      }
    }
  }

#pragma unroll
  for (int q = 0; q < 4; ++q) {
#pragma unroll
    for (int r = 0; r < 16; ++r) {
      float v = acc[q][r];
      v += __shfl_xor(v, 1);
      v += __shfl_xor(v, 2);
      v += __shfl_xor(v, 4);
      v += __shfl_xor(v, 8);
      v += __shfl_xor(v, 16);
      v += __shfl_xor(v, 32);
      acc[q][r] = v;
    }
    if (lane == 0) {
      int t = t0 + q;
      tokid[t] = ids[q];
#pragma unroll
      for (int r = 0; r < 16; ++r) {
        float v = sc[q] * acc[q][r];
        hbuf[t * RANK + r] = v;
        hb16[t * RANK + r] = f2bf(v);
      }
    }
  }
}

// ------------------------------------------------------------- main fused GEMM
// 256x256 tile, BK=64, 8 waves (2M x 4N), per-wave output 128x64. 1 block/CU
// (register budget: acc 128 + frags ~96 = the full 2-waves/SIMD allocation --
// r7 proved 2 blocks/CU is impossible at this geometry).
// r8: r6's 8-phase dual-tile skeleton + ISSUE-EARLY/CONSUME-LATE: each phase's
// ds_reads are issued one phase EARLY (before the previous phase's MFMA
// cluster); the compiler's exact counted lgkm waits drain them at the
// consuming phase, so LDS read service overlaps the ~600-cy MFMA windows
// instead of adding to them. A-quads ping-pong aqA/aqB (static names), B
// double-set bfrU/bfrV. Stage slots (2 global_load_lds each) as in r6; all
// vmcnt waits counted (4/2/4/2), never 0 in the main loop; each staged
// region's readers complete >=1 phase + barrier before its stage slot.
// XOR swizzle: phys 16B-chunk = logical ^ (row&7) on BOTH staging source and
// ds_read (rule #21; proven 0 conflicts r2-r6).
__global__ __launch_bounds__(512, 2) void gemm_fused(const unsigned short* __restrict__ A_,
                                                     const unsigned short* __restrict__ B_,
                                                     const float* __restrict__ bias,
                                                     const float* __restrict__ hbuf,
                                                     const unsigned short* __restrict__ hb16,
                                                     const int* __restrict__ tokid,
                                                     const float* __restrict__ wbt,
                                                     float* __restrict__ out) {
  __shared__ __align__(16) unsigned short As[2][BM * BK];  // 2 x 32 KB
  __shared__ __align__(16) unsigned short Bs[2][BN * BK];  // 2 x 32 KB
  __shared__ int s_nb;

  const int tid = threadIdx.x;
  const int lane = tid & 63;
  const int wave = tid >> 6;   // 0..7
  const int wr = wave >> 2;    // 0..1  M half
  const int wn = wave & 3;     // 0..3  N quarter

  // XCD-aware bijective swizzle: 512 blocks, 64-block chunk per XCD
  const int bsw = (blockIdx.x & 7) * 64 + (blockIdx.x >> 3);
  const int brow = (bsw >> 4) * BM;   // 32 M-blocks
  const int bcol = (bsw & 15) * BN;   // 16 N-blocks

  f32x4 acc[8][4] = {};

  const int g = lane >> 4;       // k-group 0..3
  const int rsel = lane & 15;    // fragment row select
  const int low3 = rsel & 7;     // swizzle phase (row & 7)

// stage ONE half-tile (128 rows x 64 k = 16 KB) of tile tt: 2 loads/thread.
#define STAGE1(dst, bufp, h, tt, src, rb0)                                             \
  {                                                                                    \
    _Pragma("unroll")                                                                  \
    for (int i = 0; i < 2; ++i) {                                                      \
      const int lin2 = i * 512 + tid;                                                  \
      const int rr = lin2 >> 3;                                                        \
      const int klog = ((lin2 & 7) ^ (rr & 7)) * 8;                                    \
      const unsigned short* gp = (src) + (size_t)((rb0) + (h) * 128 + rr) * DIN + (tt) * BK + klog; \
      __builtin_amdgcn_global_load_lds(GLB_PTR(gp), LDS_PTR(&dst[bufp][(h) * 8192 + lin2 * 8]), 16, 0, 0); \
    }                                                                                  \
  }

#define RD_B8(BF, p)                                                                   \
  _Pragma("unroll") for (int kk = 0; kk < 2; ++kk)                                     \
  _Pragma("unroll") for (int n = 0; n < 4; ++n)                                        \
    BF[n][kk] = *(const bf16x8*)(&Bs[p][(wn * 64 + n * 16 + rsel) * 64 + (((kk) * 4 + g) ^ low3) * 8]);

#define RD_A4(AQ, p, mo, kk)                                                           \
  _Pragma("unroll") for (int mi = 0; mi < 4; ++mi)                                     \
    AQ[mi] = *(const bf16x8*)(&As[p][(wr * 128 + ((mo) + mi) * 16 + rsel) * 64 + (((kk) * 4 + g) ^ low3) * 8]);

#define MFMA16(mo, kk, AQ, BF)                                                         \
  __builtin_amdgcn_s_setprio(1);                                                       \
  _Pragma("unroll") for (int mi = 0; mi < 4; ++mi)                                     \
  _Pragma("unroll") for (int n = 0; n < 4; ++n)                                        \
    acc[(mo) + mi][n] = __builtin_amdgcn_mfma_f32_16x16x32_bf16(AQ[mi], BF[n][kk],     \
                                                                acc[(mo) + mi][n], 0, 0, 0); \
  __builtin_amdgcn_s_setprio(0)

#define BAR()                                                                          \
  asm volatile("" ::: "memory");                                                       \
  __builtin_amdgcn_s_barrier();                                                        \
  asm volatile("" ::: "memory")

#define VMW(N) asm volatile("s_waitcnt vmcnt(" #N ")" ::: "memory")

  bf16x8 aqA[4], aqB[4];
  bf16x8 bfrU[4][2], bfrV[4][2];

  // ---- prologue: A(0),B(0) -> buf0; B(1) -> buf1 (12 loads)
  STAGE1(As, 0, 0, 0, A_, brow);
  STAGE1(As, 0, 1, 0, A_, brow);
  STAGE1(Bs, 0, 0, 0, B_, bcol);
  STAGE1(Bs, 0, 1, 0, B_, bcol);
  STAGE1(Bs, 1, 0, 1, B_, bcol);
  STAGE1(Bs, 1, 1, 1, B_, bcol);
  VMW(4);   // A(0),B(0) landed; B(1)'s 4 still in flight
  BAR();
  RD_B8(bfrU, 0);        // B(u0): consumed ph0-3
  RD_A4(aqA, 0, 0, 0);   // A0(u0) = m0-3 kk0: consumed ph0

  for (int j = 0; j < NPAIR - 1; ++j) {
    const int v = 2 * j + 1;
    // ph0: MFMA u q0 (aqA); read A1u->aqB; stage A(v)h0->buf1
    RD_A4(aqB, 0, 4, 0);
    STAGE1(As, 1, 0, v, A_, brow);
    BAR(); MFMA16(0, 0, aqA, bfrU); BAR();
    // ph1: MFMA u q1 (aqB); read A2u->aqA; stage A(v)h1; W1 vmcnt(4) [B(v) landed]
    RD_A4(aqA, 0, 0, 1);
    STAGE1(As, 1, 1, v, A_, brow);
    BAR(); MFMA16(4, 0, aqB, bfrU); VMW(4); BAR();
    // ph2: MFMA u q2 (aqA); read A3u->aqB + B(v)->bfrV; stage B(u+2)h0->buf0;
    //      W4 vmcnt(2) [A(v) landed]
    RD_A4(aqB, 0, 4, 1);
    RD_B8(bfrV, 1);
    STAGE1(Bs, 0, 0, v + 1, B_, bcol);
    BAR(); MFMA16(0, 1, aqA, bfrU); VMW(2); BAR();
    // ph3: MFMA u q3 (aqB); read A0v->aqA; stage B(u+2)h1->buf0
    RD_A4(aqA, 1, 0, 0);
    STAGE1(Bs, 0, 1, v + 1, B_, bcol);
    BAR(); MFMA16(4, 1, aqB, bfrU); BAR();
    // ph4: MFMA v q0 (aqA); read A1v->aqB; stage A(u+2)h0->buf0
    RD_A4(aqB, 1, 4, 0);
    STAGE1(As, 0, 0, v + 1, A_, brow);
    BAR(); MFMA16(0, 0, aqA, bfrV); BAR();
    // ph5: MFMA v q1 (aqB); read A2v->aqA; stage A(u+2)h1; W2 vmcnt(4) [B(u+2) landed]
    RD_A4(aqA, 1, 0, 1);
    STAGE1(As, 0, 1, v + 1, A_, brow);
    BAR(); MFMA16(4, 0, aqB, bfrV); VMW(4); BAR();
    // ph6: MFMA v q2 (aqA); read A3v->aqB + B(u+2)->bfrU; stage B(v+2)h0->buf1;
    //      W3 vmcnt(2) [A(u+2) landed]
    RD_A4(aqB, 1, 4, 1);
    RD_B8(bfrU, 0);
    STAGE1(Bs, 1, 0, v + 2, B_, bcol);
    BAR(); MFMA16(0, 1, aqA, bfrV); VMW(2); BAR();
    // ph7: MFMA v q3 (aqB); read A0(u+2)->aqA; stage B(v+2)h1->buf1
    RD_A4(aqA, 0, 0, 0);
    STAGE1(Bs, 1, 1, v + 2, B_, bcol);
    BAR(); MFMA16(4, 1, aqB, bfrV); BAR();
  }

  // ---- peeled final pair (u=NT-2, v=NT-1): no u+2/v+2 stages, tail drains
  {
    const int v = NT - 1;
    RD_A4(aqB, 0, 4, 0);
    STAGE1(As, 1, 0, v, A_, brow);
    BAR(); MFMA16(0, 0, aqA, bfrU); BAR();
    RD_A4(aqA, 0, 0, 1);
    STAGE1(As, 1, 1, v, A_, brow);
    BAR(); MFMA16(4, 0, aqB, bfrU); VMW(4); BAR();
    RD_A4(aqB, 0, 4, 1);
    RD_B8(bfrV, 1);
    BAR(); MFMA16(0, 1, aqA, bfrU); VMW(0); BAR();
    RD_A4(aqA, 1, 0, 0);
    BAR(); MFMA16(4, 1, aqB, bfrU); BAR();
    RD_A4(aqB, 1, 4, 0);
    BAR(); MFMA16(0, 0, aqA, bfrV); BAR();
    RD_A4(aqA, 1, 0, 1);
    BAR(); MFMA16(4, 0, aqB, bfrV); BAR();
    RD_A4(aqB, 1, 4, 1);
    BAR(); MFMA16(0, 1, aqA, bfrV); BAR();
    BAR(); MFMA16(4, 1, aqB, bfrV); BAR();
  }

  // ---- epilogue -------------------------------------------------------------
  const int rb = brow + wr * 128;
  const int cb = bcol + wn * 64;
  const int crow = g * 4;          // C/D row = (lane>>4)*4 + j
  const int ccol = rsel;

  // count adapter transitions in this block's 256 rows
  if (tid == 0) s_nb = 0;
  __syncthreads();
  if (tid >= 1 && tid < BM) {
    if (tokid[brow + tid] != tokid[brow + tid - 1]) atomicAdd(&s_nb, 1);
  }
  __syncthreads();
  const int nb = s_nb;
  const int idLo = tokid[brow];
  const int idHi = tokid[brow + BM - 1];

  float biasn[4];
#pragma unroll
  for (int n = 0; n < 4; ++n) biasn[n] = bias[cb + n * 16 + ccol];

  if (nb <= 1) {
    // ---- MFMA K=32 extension: k<16 -> adapter idLo, k>=16 -> adapter idHi
    const int myId = (g < 2) ? idLo : idHi;
    const int maskId = (g < 2) ? idLo : ((nb == 0) ? 0x80000000 : idHi);
    const float* wbase = wbt + (size_t)myId * RANK * DOUTF + (size_t)((g & 1) * 8) * DOUTF;
    bf16x8 bext[4];
#pragma unroll
    for (int n = 0; n < 4; ++n) {
      const int col = cb + n * 16 + ccol;
#pragma unroll
      for (int jj = 0; jj < 8; ++jj)
        bext[n][jj] = (short)f2bf(wbase[(size_t)jj * DOUTF + col]);
    }
#pragma unroll
    for (int m = 0; m < 8; ++m) {
      const int row = rb + m * 16 + rsel;
      const int rid = tokid[row];
      bf16x8 av = {};
      if (rid == maskId)
        av = *(const bf16x8*)(hb16 + (size_t)row * RANK + (g & 1) * 8);
#pragma unroll
      for (int n = 0; n < 4; ++n)
        acc[m][n] = __builtin_amdgcn_mfma_f32_16x16x32_bf16(av, bext[n], acc[m][n], 0, 0, 0);
    }
#pragma unroll
    for (int m = 0; m < 8; ++m) {
#pragma unroll
      for (int jj = 0; jj < 4; ++jj) {
        const int row = rb + m * 16 + crow + jj;
        float* orow = out + (size_t)row * DOUTF;
#pragma unroll
        for (int n = 0; n < 4; ++n)
          orow[cb + n * 16 + ccol] = acc[m][n][jj] + biasn[n];
      }
    }
  } else {
    // ---- rare fallback: per-row scalar LoRA
#pragma unroll
    for (int m = 0; m < 8; ++m) {
#pragma unroll
      for (int jj = 0; jj < 4; ++jj) {
        const int row = rb + m * 16 + crow + jj;
        const float4* hp = (const float4*)(hbuf + (size_t)row * RANK);
        float4 h0 = hp[0], h1 = hp[1], h2 = hp[2], h3 = hp[3];
        float hv[16] = {h0.x, h0.y, h0.z, h0.w, h1.x, h1.y, h1.z, h1.w,
                        h2.x, h2.y, h2.z, h2.w, h3.x, h3.y, h3.z, h3.w};
        const float* wrow = wbt + (size_t)tokid[row] * RANK * DOUTF;
        float* orow = out + (size_t)row * DOUTF;
#pragma unroll
        for (int n = 0; n < 4; ++n) {
          const int col = cb + n * 16 + ccol;
          float vsum = acc[m][n][jj] + biasn[n];
#pragma unroll
          for (int r = 0; r < 16; ++r) vsum += hv[r] * wrow[(size_t)r * DOUTF + col];
          orow[col] = vsum;
        }
      }
    }
  }
#undef STAGE1
#undef RD_A4
#undef RD_B8
#undef MFMA16
#undef BAR
#undef VMW
}

// ---------------------------------------------------------------------- launch
extern "C" void kernel_launch(void* const* d_in, const int* in_sizes, int n_in,
                              void* d_out, int out_size, void* d_ws, size_t ws_size,
                              hipStream_t stream) {
  const float* x       = (const float*)d_in[0];
  const float* base_w  = (const float*)d_in[1];
  const float* base_b  = (const float*)d_in[2];
  const float* wa      = (const float*)d_in[3];
  const float* wb      = (const float*)d_in[4];
  const float* scaling = (const float*)d_in[5];
  const int*   segment = (const int*)d_in[6];
  const int*   lora_id = (const int*)d_in[7];
  float* out = (float*)d_out;

  char* ws = (char*)d_ws;
  unsigned short* xb   = (unsigned short*)ws;                                  // 64 MB
  unsigned short* wbf  = (unsigned short*)(ws + (size_t)T_TOK * DIN * 2);      // 32 MB
  float* hbuf          = (float*)(ws + (size_t)T_TOK * DIN * 2 + (size_t)DOUTF * DIN * 2);
  int* tokid           = (int*)((char*)hbuf + (size_t)T_TOK * RANK * 4);
  unsigned short* hb16 = (unsigned short*)((char*)tokid + (size_t)T_TOK * 4);

  cvt_f32_bf16<<<2048, 256, 0, stream>>>(base_w, wbf, (DOUTF * DIN) / 8);
  lora_h<<<T_TOK / 16, 256, 0, stream>>>(x, wa, scaling, segment, lora_id, hbuf, hb16,
                                         tokid, xb);
  gemm_fused<<<(T_TOK / BM) * (DOUTF / BN), 512, 0, stream>>>(xb, wbf, base_b, hbuf,
                                                              hb16, tokid, wb, out);
}

// Round 9
// 357.474 us; speedup vs baseline: 7.3566x; 1.1706x over previous
//
#include <hip/hip_runtime.h>

#define T_TOK 8192
#define DIN   4096
#define DOUTF 4096
#define RANK  16

#define BM 256
#define BN 256
#define BK 128                 // i8 elements per K-tile = 128 B rows (byte-identical to r6's bf16 BK=64)
#define NT (DIN / BK)          // 32 K-tiles
#define NPAIR (NT / 2)         // 16 iterations, 2 K-tiles each

typedef __attribute__((ext_vector_type(4))) float f32x4;
typedef __attribute__((ext_vector_type(4))) int   i32x4;
typedef __attribute__((ext_vector_type(8))) short bf16x8;
typedef __attribute__((ext_vector_type(8))) unsigned short u16x8;

#define GLB_PTR(p) ((const __attribute__((address_space(1))) void*)(p))
#define LDS_PTR(p) ((__attribute__((address_space(3))) void*)(p))

__device__ __forceinline__ unsigned short f2bf(float f) {
  unsigned u = __float_as_uint(f);
  u = (u + 0x7fffu + ((u >> 16) & 1u)) >> 16;  // RNE
  return (unsigned short)u;
}

// --------------------------------------------- per-row symmetric int8 quantize
// One wave per row of 4096 fp32: reg-cache the row (64 VGPR), wave-reduce
// absmax, write i8 row + scale = absmax/127. Exactly separable scales:
// out = sx[row] * sw[col] * (int GEMM).
__global__ __launch_bounds__(256) void quant_rows(const float* __restrict__ in,
                                                  signed char* __restrict__ outq,
                                                  float* __restrict__ scl) {
  const int lane = threadIdx.x & 63;
  const int row = blockIdx.x * 4 + (threadIdx.x >> 6);
  const float* rp = in + (size_t)row * DIN;
  f32x4 v[16];
  float amax = 0.f;
#pragma unroll
  for (int it = 0; it < 16; ++it) {
    v[it] = *(const f32x4*)(rp + it * 256 + lane * 4);
#pragma unroll
    for (int e = 0; e < 4; ++e) amax = fmaxf(amax, fabsf(v[it][e]));
  }
#pragma unroll
  for (int o = 1; o < 64; o <<= 1) amax = fmaxf(amax, __shfl_xor(amax, o));
  const float inv = amax > 0.f ? 127.0f / amax : 0.f;
  if (lane == 0) scl[row] = amax * (1.0f / 127.0f);
  signed char* op = outq + (size_t)row * DIN;
#pragma unroll
  for (int it = 0; it < 16; ++it) {
    const int q0 = (int)rintf(v[it][0] * inv);
    const int q1 = (int)rintf(v[it][1] * inv);
    const int q2 = (int)rintf(v[it][2] * inv);
    const int q3 = (int)rintf(v[it][3] * inv);
    const int pk = (q0 & 255) | ((q1 & 255) << 8) | ((q2 & 255) << 16) | ((q3 & 255) << 24);
    *(int*)(op + it * 256 + lane * 4) = pk;
  }
}

// ----------------- h'[t,r] = scaling * x @ wa[id_t]; emits h' f32 + bf16 ------
__global__ __launch_bounds__(256) void lora_h(const float* __restrict__ x,
                                              const float* __restrict__ wa,
                                              const float* __restrict__ scaling,
                                              const int* __restrict__ segment,
                                              const int* __restrict__ lora_ids,
                                              float* __restrict__ hbuf,
                                              unsigned short* __restrict__ hb16,
                                              int* __restrict__ tokid) {
  const int lane = threadIdx.x & 63;
  const int wave = threadIdx.x >> 6;
  const int t0 = blockIdx.x * 16 + wave * 4;

  int ids[4]; float sc[4];
#pragma unroll
  for (int q = 0; q < 4; ++q) {
    int t = t0 + q;
    int s = 0;
#pragma unroll
    for (int i = 1; i < 8; ++i)
      if (t >= segment[i]) s = i;
    int id = lora_ids[s];
    ids[q] = id;
    sc[q] = scaling[id];
  }

  float acc[4][16];
#pragma unroll
  for (int q = 0; q < 4; ++q)
#pragma unroll
    for (int r = 0; r < 16; ++r) acc[q][r] = 0.f;

  const bool same = (ids[0] == ids[1]) && (ids[1] == ids[2]) && (ids[2] == ids[3]);
  const int dbase = lane * 4;

  if (same) {
    const float* wrow = wa + (size_t)ids[0] * DIN * RANK;
#pragma unroll 2
    for (int it = 0; it < 16; ++it) {
      const int d = it * 256 + dbase;
      f32x4 xv[4];
#pragma unroll
      for (int q = 0; q < 4; ++q)
        xv[q] = *(const f32x4*)(x + (size_t)(t0 + q) * DIN + d);
#pragma unroll
      for (int dd = 0; dd < 4; ++dd) {
        const f32x4* wp = (const f32x4*)(wrow + (size_t)(d + dd) * RANK);
        f32x4 w0 = wp[0], w1 = wp[1], w2 = wp[2], w3 = wp[3];
#pragma unroll
        for (int q = 0; q < 4; ++q) {
          const float xs = xv[q][dd];
#pragma unroll
          for (int r = 0; r < 4; ++r) {
            acc[q][r]      += xs * w0[r];
            acc[q][r + 4]  += xs * w1[r];
            acc[q][r + 8]  += xs * w2[r];
            acc[q][r + 12] += xs * w3[r];
          }
        }
      }
    }
  } else {
#pragma unroll
    for (int q = 0; q < 4; ++q) {
      const float* wrow = wa + (size_t)ids[q] * DIN * RANK;
      for (int it = 0; it < 16; ++it) {
        const int d = it * 256 + dbase;
        f32x4 xv = *(const f32x4*)(x + (size_t)(t0 + q) * DIN + d);
#pragma unroll
        for (int dd = 0; dd < 4; ++dd) {
          const f32x4* wp = (const f32x4*)(wrow + (size_t)(d + dd) * RANK);
          f32x4 w0 = wp[0], w1 = wp[1], w2 = wp[2], w3 = wp[3];
          const float xs = xv[dd];
#pragma unroll
          for (int r = 0; r < 4; ++r) {
            acc[q][r]      += xs * w0[r];
            acc[q][r + 4]  += xs * w1[r];
            acc[q][r + 8]  += xs * w2[r];
            acc[q][r + 12] += xs * w3[r];
          }
        }
      }
    }
  }

#pragma unroll
  for (int q = 0; q < 4; ++q) {
#pragma unroll
    for (int r = 0; r < 16; ++r) {
      float v = acc[q][r];
      v += __shfl_xor(v, 1);
      v += __shfl_xor(v, 2);
      v += __shfl_xor(v, 4);
      v += __shfl_xor(v, 8);
      v += __shfl_xor(v, 16);
      v += __shfl_xor(v, 32);
      acc[q][r] = v;
    }
    if (lane == 0) {
      int t = t0 + q;
      tokid[t] = ids[q];
#pragma unroll
      for (int r = 0; r < 16; ++r) {
        float v = sc[q] * acc[q][r];
        hbuf[t * RANK + r] = v;
        hb16[t * RANK + r] = f2bf(v);
      }
    }
  }
}

// ------------------------------------------------------------- main fused GEMM
// int8 NT-GEMM: iacc[t,o] = sum_k xq[t,k]*wq[o,k]; out = sx[t]*sw[o]*iacc
//             + bias[o] + LoRA (bf16 MFMA K=32 extension on the f32 acc).
// 256x256 tile, BK=128 i8 (128 B rows -- byte-identical addressing to the r6
// bf16 BK=64 skeleton), 8 waves (2M x 4N), mfma_i32_16x16x64_i8 (2xK per inst,
// i32 accum exact: |sum| <= 4096*127^2 << 2^31). r6's proven 8-phase/2-tile
// schedule verbatim: per phase {ds_reads; stage 1 half-tile (2 gload_lds);
// s_barrier; lgkmcnt(0); sched_barrier; setprio(1); 16 MFMA; setprio(0);
// s_barrier}; counted vmcnt(4) ONLY at ph3/ph7 (audited: in-flight 4->12->4,
// never drains to 0 in the main loop). XOR swizzle: phys 16B-chunk = logical
// ^ (row&7) on BOTH staging source and ds_read (r2-r6 proven 0 conflicts).
__global__ __launch_bounds__(512, 2) void gemm_fused(const signed char* __restrict__ A_,
                                                     const signed char* __restrict__ B_,
                                                     const float* __restrict__ bias,
                                                     const float* __restrict__ hbuf,
                                                     const unsigned short* __restrict__ hb16,
                                                     const int* __restrict__ tokid,
                                                     const float* __restrict__ wbt,
                                                     const float* __restrict__ sxv,
                                                     const float* __restrict__ swv,
                                                     float* __restrict__ out) {
  __shared__ __align__(16) signed char As[2][BM * BK];  // 2 x 32 KB
  __shared__ __align__(16) signed char Bs[2][BN * BK];  // 2 x 32 KB
  __shared__ int s_nb;

  const int tid = threadIdx.x;
  const int lane = tid & 63;
  const int wave = tid >> 6;   // 0..7
  const int wr = wave >> 2;    // 0..1  M half
  const int wn = wave & 3;     // 0..3  N quarter

  // XCD-aware bijective swizzle: 512 blocks, 64-block chunk per XCD
  const int bsw = (blockIdx.x & 7) * 64 + (blockIdx.x >> 3);
  const int brow = (bsw >> 4) * BM;   // 32 M-blocks
  const int bcol = (bsw & 15) * BN;   // 16 N-blocks

  i32x4 acc[8][4] = {};

  const int g = lane >> 4;       // k-group 0..3 (16 i8 each within a 64-elem kk-half)
  const int rsel = lane & 15;    // fragment row select
  const int low3 = rsel & 7;     // swizzle phase (row & 7)

// stage ONE half-tile (128 rows x 128 i8 = 16 KB) of tile tt: 2 loads/thread.
#define STAGE1(dst, bufp, h, tt, src, rb0)                                             \
  {                                                                                    \
    _Pragma("unroll")                                                                  \
    for (int i = 0; i < 2; ++i) {                                                      \
      const int lin2 = i * 512 + tid;                                                  \
      const int rr = lin2 >> 3;                                                        \
      const int klog = ((lin2 & 7) ^ (rr & 7)) * 16;  /* bytes */                      \
      const signed char* gp = (src) + (size_t)((rb0) + (h) * 128 + rr) * DIN + (tt) * BK + klog; \
      __builtin_amdgcn_global_load_lds(GLB_PTR(gp), LDS_PTR(&dst[bufp][(h) * 16384 + lin2 * 16]), 16, 0, 0); \
    }                                                                                  \
  }

#define RD_B(p)                                                                        \
  _Pragma("unroll") for (int kk = 0; kk < 2; ++kk)                                     \
  _Pragma("unroll") for (int n = 0; n < 4; ++n)                                        \
    bfr[n][kk] = *(const i32x4*)(&Bs[p][(wn * 64 + n * 16 + rsel) * BK + (((kk) * 4 + g) ^ low3) * 16]);

#define RD_A(AF, p, mo, kk)                                                            \
  _Pragma("unroll") for (int mi = 0; mi < 4; ++mi)                                     \
    AF[mi] = *(const i32x4*)(&As[p][(wr * 128 + ((mo) + mi) * 16 + rsel) * BK + (((kk) * 4 + g) ^ low3) * 16]);

#define MFMA16(mo, kk, AF)                                                             \
  _Pragma("unroll") for (int mi = 0; mi < 4; ++mi)                                     \
  _Pragma("unroll") for (int n = 0; n < 4; ++n)                                        \
    acc[(mo) + mi][n] = __builtin_amdgcn_mfma_i32_16x16x64_i8(AF[mi], bfr[n][kk],      \
                                                              acc[(mo) + mi][n], 0, 0, 0)

#define PH_OPEN()                                                                      \
  asm volatile("" ::: "memory");                                                       \
  __builtin_amdgcn_s_barrier();                                                        \
  asm volatile("s_waitcnt lgkmcnt(0)" ::: "memory");                                   \
  __builtin_amdgcn_sched_barrier(0);                                                   \
  __builtin_amdgcn_s_setprio(1)

#define PH_CLOSE()                                                                     \
  __builtin_amdgcn_s_setprio(0);                                                       \
  asm volatile("" ::: "memory");                                                       \
  __builtin_amdgcn_s_barrier();                                                        \
  asm volatile("" ::: "memory")

#define PH_CLOSE_VM(N)                                                                 \
  __builtin_amdgcn_s_setprio(0);                                                       \
  asm volatile("s_waitcnt vmcnt(" #N ")" ::: "memory");                                \
  __builtin_amdgcn_s_barrier();                                                        \
  asm volatile("" ::: "memory")

  // ---- prologue: A(0),B(0) -> buf0; B(1) -> buf1 (12 loads)
  STAGE1(As, 0, 0, 0, A_, brow);
  STAGE1(As, 0, 1, 0, A_, brow);
  STAGE1(Bs, 0, 0, 0, B_, bcol);
  STAGE1(Bs, 0, 1, 0, B_, bcol);
  STAGE1(Bs, 1, 0, 1, B_, bcol);
  STAGE1(Bs, 1, 1, 1, B_, bcol);
  asm volatile("s_waitcnt vmcnt(4)" ::: "memory");  // tile0 landed; B(1) in flight
  __builtin_amdgcn_s_barrier();
  asm volatile("" ::: "memory");

  for (int j = 0; j < NPAIR - 1; ++j) {
    const int v = 2 * j + 1;
    i32x4 bfr[4][2], afA[4], afB[4];
    // ph0: buf0 kk0 m0-3; stage A(v)h0->buf1
    RD_B(0); RD_A(afA, 0, 0, 0);
    STAGE1(As, 1, 0, v, A_, brow);
    PH_OPEN(); MFMA16(0, 0, afA); PH_CLOSE();
    // ph1: stage A(v)h1
    RD_A(afB, 0, 4, 0);
    STAGE1(As, 1, 1, v, A_, brow);
    PH_OPEN(); MFMA16(4, 0, afB); PH_CLOSE();
    // ph2: stage B(u+2)h0->buf0
    RD_A(afA, 0, 0, 1);
    STAGE1(Bs, 0, 0, v + 1, B_, bcol);
    PH_OPEN(); MFMA16(0, 1, afA); PH_CLOSE();
    // ph3: stage B(u+2)h1->buf0; counted wait: B(v),A(v) landed; B(u+2) in flight
    RD_A(afB, 0, 4, 1);
    STAGE1(Bs, 0, 1, v + 1, B_, bcol);
    PH_OPEN(); MFMA16(4, 1, afB); PH_CLOSE_VM(4);
    // ph4: buf1 kk0 m0-3; stage A(u+2)h0->buf0
    RD_B(1); RD_A(afA, 1, 0, 0);
    STAGE1(As, 0, 0, v + 1, A_, brow);
    PH_OPEN(); MFMA16(0, 0, afA); PH_CLOSE();
    // ph5: stage A(u+2)h1
    RD_A(afB, 1, 4, 0);
    STAGE1(As, 0, 1, v + 1, A_, brow);
    PH_OPEN(); MFMA16(4, 0, afB); PH_CLOSE();
    // ph6: stage B(v+2)h0->buf1
    RD_A(afA, 1, 0, 1);
    STAGE1(Bs, 1, 0, v + 2, B_, bcol);
    PH_OPEN(); MFMA16(0, 1, afA); PH_CLOSE();
    // ph7: stage B(v+2)h1->buf1; counted wait: B(u+2),A(u+2) landed
    RD_A(afB, 1, 4, 1);
    STAGE1(Bs, 1, 1, v + 2, B_, bcol);
    PH_OPEN(); MFMA16(4, 1, afB); PH_CLOSE_VM(4);
  }

  // ---- peeled final pair (u=NT-2, v=NT-1): stage only A(v); drain at ph3
  {
    const int v = NT - 1;
    i32x4 bfr[4][2], afA[4], afB[4];
    RD_B(0); RD_A(afA, 0, 0, 0);
    STAGE1(As, 1, 0, v, A_, brow);
    PH_OPEN(); MFMA16(0, 0, afA); PH_CLOSE();
    RD_A(afB, 0, 4, 0);
    STAGE1(As, 1, 1, v, A_, brow);
    PH_OPEN(); MFMA16(4, 0, afB); PH_CLOSE();
    RD_A(afA, 0, 0, 1);
    PH_OPEN(); MFMA16(0, 1, afA); PH_CLOSE();
    RD_A(afB, 0, 4, 1);
    PH_OPEN(); MFMA16(4, 1, afB); PH_CLOSE_VM(0);
    RD_B(1); RD_A(afA, 1, 0, 0);
    PH_OPEN(); MFMA16(0, 0, afA); PH_CLOSE();
    RD_A(afB, 1, 4, 0);
    PH_OPEN(); MFMA16(4, 0, afB); PH_CLOSE();
    RD_A(afA, 1, 0, 1);
    PH_OPEN(); MFMA16(0, 1, afA); PH_CLOSE();
    RD_A(afB, 1, 4, 1);
    PH_OPEN(); MFMA16(4, 1, afB); PH_CLOSE();
  }

  // ---- epilogue -------------------------------------------------------------
  const int rb = brow + wr * 128;
  const int cb = bcol + wn * 64;
  const int crow = g * 4;          // C/D row = (lane>>4)*4 + j (dtype-independent)
  const int ccol = rsel;

  // count adapter transitions in this block's 256 rows
  if (tid == 0) s_nb = 0;
  __syncthreads();
  if (tid >= 1 && tid < BM) {
    if (tokid[brow + tid] != tokid[brow + tid - 1]) atomicAdd(&s_nb, 1);
  }
  __syncthreads();
  const int nb = s_nb;
  const int idLo = tokid[brow];
  const int idHi = tokid[brow + BM - 1];

  float biasn[4], swn[4];
#pragma unroll
  for (int n = 0; n < 4; ++n) {
    biasn[n] = bias[cb + n * 16 + ccol];
    swn[n] = swv[cb + n * 16 + ccol];
  }

  // convert i32 acc -> f32 with separable scales (in place, per-m)
  f32x4 facc[8][4];
#pragma unroll
  for (int m = 0; m < 8; ++m) {
    float sxr[4];
#pragma unroll
    for (int jj = 0; jj < 4; ++jj) sxr[jj] = sxv[rb + m * 16 + crow + jj];
#pragma unroll
    for (int n = 0; n < 4; ++n)
#pragma unroll
      for (int jj = 0; jj < 4; ++jj)
        facc[m][n][jj] = (float)acc[m][n][jj] * (sxr[jj] * swn[n]);
  }

  if (nb <= 1) {
    // ---- MFMA K=32 extension: k<16 -> adapter idLo, k>=16 -> adapter idHi
    const int myId = (g < 2) ? idLo : idHi;
    const int maskId = (g < 2) ? idLo : ((nb == 0) ? 0x80000000 : idHi);
    const float* wbase = wbt + (size_t)myId * RANK * DOUTF + (size_t)((g & 1) * 8) * DOUTF;
    bf16x8 bext[4];
#pragma unroll
    for (int n = 0; n < 4; ++n) {
      const int col = cb + n * 16 + ccol;
#pragma unroll
      for (int jj = 0; jj < 8; ++jj)
        bext[n][jj] = (short)f2bf(wbase[(size_t)jj * DOUTF + col]);
    }
#pragma unroll
    for (int m = 0; m < 8; ++m) {
      const int row = rb + m * 16 + rsel;
      const int rid = tokid[row];
      bf16x8 av = {};
      if (rid == maskId)
        av = *(const bf16x8*)(hb16 + (size_t)row * RANK + (g & 1) * 8);
#pragma unroll
      for (int n = 0; n < 4; ++n)
        facc[m][n] = __builtin_amdgcn_mfma_f32_16x16x32_bf16(av, bext[n], facc[m][n], 0, 0, 0);
    }
#pragma unroll
    for (int m = 0; m < 8; ++m) {
#pragma unroll
      for (int jj = 0; jj < 4; ++jj) {
        const int row = rb + m * 16 + crow + jj;
        float* orow = out + (size_t)row * DOUTF;
#pragma unroll
        for (int n = 0; n < 4; ++n)
          orow[cb + n * 16 + ccol] = facc[m][n][jj] + biasn[n];
      }
    }
  } else {
    // ---- rare fallback: per-row scalar LoRA
#pragma unroll
    for (int m = 0; m < 8; ++m) {
#pragma unroll
      for (int jj = 0; jj < 4; ++jj) {
        const int row = rb + m * 16 + crow + jj;
        const float4* hp = (const float4*)(hbuf + (size_t)row * RANK);
        float4 h0 = hp[0], h1 = hp[1], h2 = hp[2], h3 = hp[3];
        float hv[16] = {h0.x, h0.y, h0.z, h0.w, h1.x, h1.y, h1.z, h1.w,
                        h2.x, h2.y, h2.z, h2.w, h3.x, h3.y, h3.z, h3.w};
        const float* wrow = wbt + (size_t)tokid[row] * RANK * DOUTF;
        float* orow = out + (size_t)row * DOUTF;
#pragma unroll
        for (int n = 0; n < 4; ++n) {
          const int col = cb + n * 16 + ccol;
          float vsum = facc[m][n][jj] + biasn[n];
#pragma unroll
          for (int r = 0; r < 16; ++r) vsum += hv[r] * wrow[(size_t)r * DOUTF + col];
          orow[col] = vsum;
        }
      }
    }
  }
#undef STAGE1
#undef RD_A
#undef RD_B
#undef MFMA16
#undef PH_OPEN
#undef PH_CLOSE
#undef PH_CLOSE_VM
}

// ---------------------------------------------------------------------- launch
extern "C" void kernel_launch(void* const* d_in, const int* in_sizes, int n_in,
                              void* d_out, int out_size, void* d_ws, size_t ws_size,
                              hipStream_t stream) {
  const float* x       = (const float*)d_in[0];
  const float* base_w  = (const float*)d_in[1];
  const float* base_b  = (const float*)d_in[2];
  const float* wa      = (const float*)d_in[3];
  const float* wb      = (const float*)d_in[4];
  const float* scaling = (const float*)d_in[5];
  const int*   segment = (const int*)d_in[6];
  const int*   lora_id = (const int*)d_in[7];
  float* out = (float*)d_out;

  char* ws = (char*)d_ws;
  signed char* xq = (signed char*)ws;                                  // 32 MB
  signed char* wq = (signed char*)(ws + (size_t)T_TOK * DIN);          // 16 MB
  float* sx   = (float*)(ws + (size_t)T_TOK * DIN + (size_t)DOUTF * DIN);
  float* sw   = sx + T_TOK;
  float* hbuf = sw + DOUTF;
  int* tokid  = (int*)(hbuf + (size_t)T_TOK * RANK);
  unsigned short* hb16 = (unsigned short*)(tokid + T_TOK);

  quant_rows<<<T_TOK / 4, 256, 0, stream>>>(x, xq, sx);
  quant_rows<<<DOUTF / 4, 256, 0, stream>>>(base_w, wq, sw);
  lora_h<<<T_TOK / 16, 256, 0, stream>>>(x, wa, scaling, segment, lora_id, hbuf, hb16,
                                         tokid);
  gemm_fused<<<(T_TOK / BM) * (DOUTF / BN), 512, 0, stream>>>(xq, wq, base_b, hbuf,
                                                              hb16, tokid, wb, sx, sw,
                                                              out);
}

// Round 10
// 298.969 us; speedup vs baseline: 8.7962x; 1.1957x over previous
//
#include <hip/hip_runtime.h>

#define T_TOK 8192
#define DIN   4096
#define DOUTF 4096
#define RANK  16

#define BM 256
#define BN 256
#define BK 128                 // i8 elements per K-tile = 128 B rows
#define NT (DIN / BK)          // 32 K-tiles
#define NPAIR (NT / 2)         // 16 iterations, 2 K-tiles each

typedef __attribute__((ext_vector_type(4))) float f32x4;
typedef __attribute__((ext_vector_type(4))) int   i32x4;
typedef __attribute__((ext_vector_type(8))) short bf16x8;

#define GLB_PTR(p) ((const __attribute__((address_space(1))) void*)(p))
#define LDS_PTR(p) ((__attribute__((address_space(3))) void*)(p))

__device__ __forceinline__ unsigned short f2bf(float f) {
  unsigned u = __float_as_uint(f);
  u = (u + 0x7fffu + ((u >> 16) & 1u)) >> 16;  // RNE
  return (unsigned short)u;
}

// ---------------------------------------------------------------- fused prep
// blocks [0,512): lora_h + x-quant (pass1 streams x f32 accumulating LoRA acc
//   AND per-token absmax; pass2 re-reads the 4 just-touched rows -- L2/L3-hot,
//   x fits the 256MB L3 -- and writes i8). x is read from HBM ONCE total.
// blocks [512,1536): per-row quant of base_w (reg-cached row, wave absmax).
__global__ __launch_bounds__(256) void prep(const float* __restrict__ x,
                                            const float* __restrict__ base_w,
                                            const float* __restrict__ wa,
                                            const float* __restrict__ scaling,
                                            const int* __restrict__ segment,
                                            const int* __restrict__ lora_ids,
                                            signed char* __restrict__ xq,
                                            float* __restrict__ sx,
                                            signed char* __restrict__ wq,
                                            float* __restrict__ sw,
                                            float* __restrict__ hbuf,
                                            unsigned short* __restrict__ hb16,
                                            int* __restrict__ tokid) {
  const int lane = threadIdx.x & 63;
  const int wave = threadIdx.x >> 6;

  if (blockIdx.x >= 512) {
    // ---------------- quant_w path: one row per wave, reg-cached
    const int row = (blockIdx.x - 512) * 4 + wave;
    const float* rp = base_w + (size_t)row * DIN;
    f32x4 v[16];
    float amax = 0.f;
#pragma unroll
    for (int it = 0; it < 16; ++it) {
      v[it] = *(const f32x4*)(rp + it * 256 + lane * 4);
#pragma unroll
      for (int e = 0; e < 4; ++e) amax = fmaxf(amax, fabsf(v[it][e]));
    }
#pragma unroll
    for (int o = 1; o < 64; o <<= 1) amax = fmaxf(amax, __shfl_xor(amax, o));
    const float inv = amax > 0.f ? 127.0f / amax : 0.f;
    if (lane == 0) sw[row] = amax * (1.0f / 127.0f);
    signed char* op = wq + (size_t)row * DIN;
#pragma unroll
    for (int it = 0; it < 16; ++it) {
      const int q0 = (int)rintf(v[it][0] * inv);
      const int q1 = (int)rintf(v[it][1] * inv);
      const int q2 = (int)rintf(v[it][2] * inv);
      const int q3 = (int)rintf(v[it][3] * inv);
      *(int*)(op + it * 256 + lane * 4) =
          (q0 & 255) | ((q1 & 255) << 8) | ((q2 & 255) << 16) | ((q3 & 255) << 24);
    }
    return;
  }

  // ---------------- lora + x-quant path: 4 consecutive tokens per wave
  const int t0 = blockIdx.x * 16 + wave * 4;

  int ids[4]; float sc[4];
#pragma unroll
  for (int q = 0; q < 4; ++q) {
    int t = t0 + q;
    int s = 0;
#pragma unroll
    for (int i = 1; i < 8; ++i)
      if (t >= segment[i]) s = i;
    int id = lora_ids[s];
    ids[q] = id;
    sc[q] = scaling[id];
  }

  float acc[4][16];
  float amax[4] = {0.f, 0.f, 0.f, 0.f};
#pragma unroll
  for (int q = 0; q < 4; ++q)
#pragma unroll
    for (int r = 0; r < 16; ++r) acc[q][r] = 0.f;

  const bool same = (ids[0] == ids[1]) && (ids[1] == ids[2]) && (ids[2] == ids[3]);
  const int dbase = lane * 4;

  if (same) {
    const float* wrow = wa + (size_t)ids[0] * DIN * RANK;
#pragma unroll 2
    for (int it = 0; it < 16; ++it) {
      const int d = it * 256 + dbase;
      f32x4 xv[4];
#pragma unroll
      for (int q = 0; q < 4; ++q) {
        xv[q] = *(const f32x4*)(x + (size_t)(t0 + q) * DIN + d);
#pragma unroll
        for (int e = 0; e < 4; ++e) amax[q] = fmaxf(amax[q], fabsf(xv[q][e]));
      }
#pragma unroll
      for (int dd = 0; dd < 4; ++dd) {
        const f32x4* wp = (const f32x4*)(wrow + (size_t)(d + dd) * RANK);
        f32x4 w0 = wp[0], w1 = wp[1], w2 = wp[2], w3 = wp[3];
#pragma unroll
        for (int q = 0; q < 4; ++q) {
          const float xs = xv[q][dd];
#pragma unroll
          for (int r = 0; r < 4; ++r) {
            acc[q][r]      += xs * w0[r];
            acc[q][r + 4]  += xs * w1[r];
            acc[q][r + 8]  += xs * w2[r];
            acc[q][r + 12] += xs * w3[r];
          }
        }
      }
    }
  } else {
#pragma unroll
    for (int q = 0; q < 4; ++q) {
      const float* wrow = wa + (size_t)ids[q] * DIN * RANK;
      for (int it = 0; it < 16; ++it) {
        const int d = it * 256 + dbase;
        f32x4 xv = *(const f32x4*)(x + (size_t)(t0 + q) * DIN + d);
#pragma unroll
        for (int e = 0; e < 4; ++e) amax[q] = fmaxf(amax[q], fabsf(xv[e]));
#pragma unroll
        for (int dd = 0; dd < 4; ++dd) {
          const f32x4* wp = (const f32x4*)(wrow + (size_t)(d + dd) * RANK);
          f32x4 w0 = wp[0], w1 = wp[1], w2 = wp[2], w3 = wp[3];
          const float xs = xv[dd];
#pragma unroll
          for (int r = 0; r < 4; ++r) {
            acc[q][r]      += xs * w0[r];
            acc[q][r + 4]  += xs * w1[r];
            acc[q][r + 8]  += xs * w2[r];
            acc[q][r + 12] += xs * w3[r];
          }
        }
      }
    }
  }

  // h reductions + writes
#pragma unroll
  for (int q = 0; q < 4; ++q) {
#pragma unroll
    for (int r = 0; r < 16; ++r) {
      float v = acc[q][r];
      v += __shfl_xor(v, 1);
      v += __shfl_xor(v, 2);
      v += __shfl_xor(v, 4);
      v += __shfl_xor(v, 8);
      v += __shfl_xor(v, 16);
      v += __shfl_xor(v, 32);
      acc[q][r] = v;
    }
    if (lane == 0) {
      int t = t0 + q;
      tokid[t] = ids[q];
#pragma unroll
      for (int r = 0; r < 16; ++r) {
        float v = sc[q] * acc[q][r];
        hbuf[t * RANK + r] = v;
        hb16[t * RANK + r] = f2bf(v);
      }
    }
  }

  // quant pass: rows just streamed -> L2/L3-hot re-read
#pragma unroll
  for (int q = 0; q < 4; ++q) {
    float am = amax[q];
#pragma unroll
    for (int o = 1; o < 64; o <<= 1) am = fmaxf(am, __shfl_xor(am, o));
    const float inv = am > 0.f ? 127.0f / am : 0.f;
    if (lane == 0) sx[t0 + q] = am * (1.0f / 127.0f);
    const float* rp = x + (size_t)(t0 + q) * DIN;
    signed char* op = xq + (size_t)(t0 + q) * DIN;
#pragma unroll 4
    for (int it = 0; it < 16; ++it) {
      f32x4 v = *(const f32x4*)(rp + it * 256 + dbase);
      const int q0 = (int)rintf(v[0] * inv);
      const int q1 = (int)rintf(v[1] * inv);
      const int q2 = (int)rintf(v[2] * inv);
      const int q3 = (int)rintf(v[3] * inv);
      *(int*)(op + it * 256 + dbase) =
          (q0 & 255) | ((q1 & 255) << 8) | ((q2 & 255) << 16) | ((q3 & 255) << 24);
    }
  }
}

// ------------------------------------------------------------- main fused GEMM
// (unchanged from round 9 -- prediction matched: 197us, MfmaUtil 28.6, 0 conflicts)
// int8 NT-GEMM: iacc[t,o] = sum_k xq[t,k]*wq[o,k]; out = sx[t]*sw[o]*iacc
//             + bias[o] + LoRA (bf16 MFMA K=32 extension on the f32 acc).
__global__ __launch_bounds__(512, 2) void gemm_fused(const signed char* __restrict__ A_,
                                                     const signed char* __restrict__ B_,
                                                     const float* __restrict__ bias,
                                                     const float* __restrict__ hbuf,
                                                     const unsigned short* __restrict__ hb16,
                                                     const int* __restrict__ tokid,
                                                     const float* __restrict__ wbt,
                                                     const float* __restrict__ sxv,
                                                     const float* __restrict__ swv,
                                                     float* __restrict__ out) {
  __shared__ __align__(16) signed char As[2][BM * BK];  // 2 x 32 KB
  __shared__ __align__(16) signed char Bs[2][BN * BK];  // 2 x 32 KB
  __shared__ int s_nb;

  const int tid = threadIdx.x;
  const int lane = tid & 63;
  const int wave = tid >> 6;   // 0..7
  const int wr = wave >> 2;    // 0..1  M half
  const int wn = wave & 3;     // 0..3  N quarter

  // XCD-aware bijective swizzle: 512 blocks, 64-block chunk per XCD
  const int bsw = (blockIdx.x & 7) * 64 + (blockIdx.x >> 3);
  const int brow = (bsw >> 4) * BM;   // 32 M-blocks
  const int bcol = (bsw & 15) * BN;   // 16 N-blocks

  i32x4 acc[8][4] = {};

  const int g = lane >> 4;       // k-group 0..3
  const int rsel = lane & 15;    // fragment row select
  const int low3 = rsel & 7;     // swizzle phase (row & 7)

#define STAGE1(dst, bufp, h, tt, src, rb0)                                             \
  {                                                                                    \
    _Pragma("unroll")                                                                  \
    for (int i = 0; i < 2; ++i) {                                                      \
      const int lin2 = i * 512 + tid;                                                  \
      const int rr = lin2 >> 3;                                                        \
      const int klog = ((lin2 & 7) ^ (rr & 7)) * 16;  /* bytes */                      \
      const signed char* gp = (src) + (size_t)((rb0) + (h) * 128 + rr) * DIN + (tt) * BK + klog; \
      __builtin_amdgcn_global_load_lds(GLB_PTR(gp), LDS_PTR(&dst[bufp][(h) * 16384 + lin2 * 16]), 16, 0, 0); \
    }                                                                                  \
  }

#define RD_B(p)                                                                        \
  _Pragma("unroll") for (int kk = 0; kk < 2; ++kk)                                     \
  _Pragma("unroll") for (int n = 0; n < 4; ++n)                                        \
    bfr[n][kk] = *(const i32x4*)(&Bs[p][(wn * 64 + n * 16 + rsel) * BK + (((kk) * 4 + g) ^ low3) * 16]);

#define RD_A(AF, p, mo, kk)                                                            \
  _Pragma("unroll") for (int mi = 0; mi < 4; ++mi)                                     \
    AF[mi] = *(const i32x4*)(&As[p][(wr * 128 + ((mo) + mi) * 16 + rsel) * BK + (((kk) * 4 + g) ^ low3) * 16]);

#define MFMA16(mo, kk, AF)                                                             \
  _Pragma("unroll") for (int mi = 0; mi < 4; ++mi)                                     \
  _Pragma("unroll") for (int n = 0; n < 4; ++n)                                        \
    acc[(mo) + mi][n] = __builtin_amdgcn_mfma_i32_16x16x64_i8(AF[mi], bfr[n][kk],      \
                                                              acc[(mo) + mi][n], 0, 0, 0)

#define PH_OPEN()                                                                      \
  asm volatile("" ::: "memory");                                                       \
  __builtin_amdgcn_s_barrier();                                                        \
  asm volatile("s_waitcnt lgkmcnt(0)" ::: "memory");                                   \
  __builtin_amdgcn_sched_barrier(0);                                                   \
  __builtin_amdgcn_s_setprio(1)

#define PH_CLOSE()                                                                     \
  __builtin_amdgcn_s_setprio(0);                                                       \
  asm volatile("" ::: "memory");                                                       \
  __builtin_amdgcn_s_barrier();                                                        \
  asm volatile("" ::: "memory")

#define PH_CLOSE_VM(N)                                                                 \
  __builtin_amdgcn_s_setprio(0);                                                       \
  asm volatile("s_waitcnt vmcnt(" #N ")" ::: "memory");                                \
  __builtin_amdgcn_s_barrier();                                                        \
  asm volatile("" ::: "memory")

  // ---- prologue: A(0),B(0) -> buf0; B(1) -> buf1 (12 loads)
  STAGE1(As, 0, 0, 0, A_, brow);
  STAGE1(As, 0, 1, 0, A_, brow);
  STAGE1(Bs, 0, 0, 0, B_, bcol);
  STAGE1(Bs, 0, 1, 0, B_, bcol);
  STAGE1(Bs, 1, 0, 1, B_, bcol);
  STAGE1(Bs, 1, 1, 1, B_, bcol);
  asm volatile("s_waitcnt vmcnt(4)" ::: "memory");
  __builtin_amdgcn_s_barrier();
  asm volatile("" ::: "memory");

  for (int j = 0; j < NPAIR - 1; ++j) {
    const int v = 2 * j + 1;
    i32x4 bfr[4][2], afA[4], afB[4];
    RD_B(0); RD_A(afA, 0, 0, 0);
    STAGE1(As, 1, 0, v, A_, brow);
    PH_OPEN(); MFMA16(0, 0, afA); PH_CLOSE();
    RD_A(afB, 0, 4, 0);
    STAGE1(As, 1, 1, v, A_, brow);
    PH_OPEN(); MFMA16(4, 0, afB); PH_CLOSE();
    RD_A(afA, 0, 0, 1);
    STAGE1(Bs, 0, 0, v + 1, B_, bcol);
    PH_OPEN(); MFMA16(0, 1, afA); PH_CLOSE();
    RD_A(afB, 0, 4, 1);
    STAGE1(Bs, 0, 1, v + 1, B_, bcol);
    PH_OPEN(); MFMA16(4, 1, afB); PH_CLOSE_VM(4);
    RD_B(1); RD_A(afA, 1, 0, 0);
    STAGE1(As, 0, 0, v + 1, A_, brow);
    PH_OPEN(); MFMA16(0, 0, afA); PH_CLOSE();
    RD_A(afB, 1, 4, 0);
    STAGE1(As, 0, 1, v + 1, A_, brow);
    PH_OPEN(); MFMA16(4, 0, afB); PH_CLOSE();
    RD_A(afA, 1, 0, 1);
    STAGE1(Bs, 1, 0, v + 2, B_, bcol);
    PH_OPEN(); MFMA16(0, 1, afA); PH_CLOSE();
    RD_A(afB, 1, 4, 1);
    STAGE1(Bs, 1, 1, v + 2, B_, bcol);
    PH_OPEN(); MFMA16(4, 1, afB); PH_CLOSE_VM(4);
  }

  // ---- peeled final pair
  {
    const int v = NT - 1;
    i32x4 bfr[4][2], afA[4], afB[4];
    RD_B(0); RD_A(afA, 0, 0, 0);
    STAGE1(As, 1, 0, v, A_, brow);
    PH_OPEN(); MFMA16(0, 0, afA); PH_CLOSE();
    RD_A(afB, 0, 4, 0);
    STAGE1(As, 1, 1, v, A_, brow);
    PH_OPEN(); MFMA16(4, 0, afB); PH_CLOSE();
    RD_A(afA, 0, 0, 1);
    PH_OPEN(); MFMA16(0, 1, afA); PH_CLOSE();
    RD_A(afB, 0, 4, 1);
    PH_OPEN(); MFMA16(4, 1, afB); PH_CLOSE_VM(0);
    RD_B(1); RD_A(afA, 1, 0, 0);
    PH_OPEN(); MFMA16(0, 0, afA); PH_CLOSE();
    RD_A(afB, 1, 4, 0);
    PH_OPEN(); MFMA16(4, 0, afB); PH_CLOSE();
    RD_A(afA, 1, 0, 1);
    PH_OPEN(); MFMA16(0, 1, afA); PH_CLOSE();
    RD_A(afB, 1, 4, 1);
    PH_OPEN(); MFMA16(4, 1, afB); PH_CLOSE();
  }

  // ---- epilogue -------------------------------------------------------------
  const int rb = brow + wr * 128;
  const int cb = bcol + wn * 64;
  const int crow = g * 4;
  const int ccol = rsel;

  if (tid == 0) s_nb = 0;
  __syncthreads();
  if (tid >= 1 && tid < BM) {
    if (tokid[brow + tid] != tokid[brow + tid - 1]) atomicAdd(&s_nb, 1);
  }
  __syncthreads();
  const int nb = s_nb;
  const int idLo = tokid[brow];
  const int idHi = tokid[brow + BM - 1];

  float biasn[4], swn[4];
#pragma unroll
  for (int n = 0; n < 4; ++n) {
    biasn[n] = bias[cb + n * 16 + ccol];
    swn[n] = swv[cb + n * 16 + ccol];
  }

  f32x4 facc[8][4];
#pragma unroll
  for (int m = 0; m < 8; ++m) {
    float sxr[4];
#pragma unroll
    for (int jj = 0; jj < 4; ++jj) sxr[jj] = sxv[rb + m * 16 + crow + jj];
#pragma unroll
    for (int n = 0; n < 4; ++n)
#pragma unroll
      for (int jj = 0; jj < 4; ++jj)
        facc[m][n][jj] = (float)acc[m][n][jj] * (sxr[jj] * swn[n]);
  }

  if (nb <= 1) {
    const int myId = (g < 2) ? idLo : idHi;
    const int maskId = (g < 2) ? idLo : ((nb == 0) ? 0x80000000 : idHi);
    const float* wbase = wbt + (size_t)myId * RANK * DOUTF + (size_t)((g & 1) * 8) * DOUTF;
    bf16x8 bext[4];
#pragma unroll
    for (int n = 0; n < 4; ++n) {
      const int col = cb + n * 16 + ccol;
#pragma unroll
      for (int jj = 0; jj < 8; ++jj)
        bext[n][jj] = (short)f2bf(wbase[(size_t)jj * DOUTF + col]);
    }
#pragma unroll
    for (int m = 0; m < 8; ++m) {
      const int row = rb + m * 16 + rsel;
      const int rid = tokid[row];
      bf16x8 av = {};
      if (rid == maskId)
        av = *(const bf16x8*)(hb16 + (size_t)row * RANK + (g & 1) * 8);
#pragma unroll
      for (int n = 0; n < 4; ++n)
        facc[m][n] = __builtin_amdgcn_mfma_f32_16x16x32_bf16(av, bext[n], facc[m][n], 0, 0, 0);
    }
#pragma unroll
    for (int m = 0; m < 8; ++m) {
#pragma unroll
      for (int jj = 0; jj < 4; ++jj) {
        const int row = rb + m * 16 + crow + jj;
        float* orow = out + (size_t)row * DOUTF;
#pragma unroll
        for (int n = 0; n < 4; ++n)
          orow[cb + n * 16 + ccol] = facc[m][n][jj] + biasn[n];
      }
    }
  } else {
#pragma unroll
    for (int m = 0; m < 8; ++m) {
#pragma unroll
      for (int jj = 0; jj < 4; ++jj) {
        const int row = rb + m * 16 + crow + jj;
        const float4* hp = (const float4*)(hbuf + (size_t)row * RANK);
        float4 h0 = hp[0], h1 = hp[1], h2 = hp[2], h3 = hp[3];
        float hv[16] = {h0.x, h0.y, h0.z, h0.w, h1.x, h1.y, h1.z, h1.w,
                        h2.x, h2.y, h2.z, h2.w, h3.x, h3.y, h3.z, h3.w};
        const float* wrow = wbt + (size_t)tokid[row] * RANK * DOUTF;
        float* orow = out + (size_t)row * DOUTF;
#pragma unroll
        for (int n = 0; n < 4; ++n) {
          const int col = cb + n * 16 + ccol;
          float vsum = facc[m][n][jj] + biasn[n];
#pragma unroll
          for (int r = 0; r < 16; ++r) vsum += hv[r] * wrow[(size_t)r * DOUTF + col];
          orow[col] = vsum;
        }
      }
    }
  }
#undef STAGE1
#undef RD_A
#undef RD_B
#undef MFMA16
#undef PH_OPEN
#undef PH_CLOSE
#undef PH_CLOSE_VM
}

// ---------------------------------------------------------------------- launch
extern "C" void kernel_launch(void* const* d_in, const int* in_sizes, int n_in,
                              void* d_out, int out_size, void* d_ws, size_t ws_size,
                              hipStream_t stream) {
  const float* x       = (const float*)d_in[0];
  const float* base_w  = (const float*)d_in[1];
  const float* base_b  = (const float*)d_in[2];
  const float* wa      = (const float*)d_in[3];
  const float* wb      = (const float*)d_in[4];
  const float* scaling = (const float*)d_in[5];
  const int*   segment = (const int*)d_in[6];
  const int*   lora_id = (const int*)d_in[7];
  float* out = (float*)d_out;

  char* ws = (char*)d_ws;
  signed char* xq = (signed char*)ws;                                  // 32 MB
  signed char* wq = (signed char*)(ws + (size_t)T_TOK * DIN);          // 16 MB
  float* sx   = (float*)(ws + (size_t)T_TOK * DIN + (size_t)DOUTF * DIN);
  float* sw   = sx + T_TOK;
  float* hbuf = sw + DOUTF;
  int* tokid  = (int*)(hbuf + (size_t)T_TOK * RANK);
  unsigned short* hb16 = (unsigned short*)(tokid + T_TOK);

  prep<<<512 + DOUTF / 4, 256, 0, stream>>>(x, base_w, wa, scaling, segment, lora_id,
                                            xq, sx, wq, sw, hbuf, hb16, tokid);
  gemm_fused<<<(T_TOK / BM) * (DOUTF / BN), 512, 0, stream>>>(xq, wq, base_b, hbuf,
                                                              hb16, tokid, wb, sx, sw,
                                                              out);
}